// Round 16
// baseline (157.485 us; speedup 1.0000x reference)
//
#include <hip/hip_runtime.h>
#include <math.h>

#define N 2048
#define D 32
#define R 64
#define TI 16           // rows per attn block (halves column-load total vs 8)
#define JS 8            // j-splits
#define JT (N / JS)     // 256 j's per block
#define NW (N / 64)     // 32 u64 mask words per row

// (1/sqrt(d)) * log2(e), folded into stored Q
#define SCL (0.17677669529663687f * 1.4426950408889634f)
#define LOG2E 1.4426950408889634f

typedef float f2 __attribute__((ext_vector_type(2)));
typedef float f4 __attribute__((ext_vector_type(4)));

static __device__ __forceinline__ float fexp2(float x) {
    return __builtin_amdgcn_exp2f(x);
}

// ---------------------------------------------------------------- K0: pack attendable(mask==0) into bits
__global__ __launch_bounds__(256) void mask_pack_kernel(
    const int* __restrict__ mask, unsigned long long* __restrict__ mb)
{
    const size_t w   = ((size_t)blockIdx.x * 256 + threadIdx.x) >> 6; // global wave id
    const int   lane = threadIdx.x & 63;
    const size_t base = w * 256;
    const unsigned long long w0 = __ballot(mask[base +   0 + lane] == 0);
    const unsigned long long w1 = __ballot(mask[base +  64 + lane] == 0);
    const unsigned long long w2 = __ballot(mask[base + 128 + lane] == 0);
    const unsigned long long w3 = __ballot(mask[base + 192 + lane] == 0);
    const unsigned long long sel = (lane == 0) ? w0 : (lane == 1) ? w1
                                 : (lane == 2) ? w2 : w3;
    if (lane < 4) mb[w * 4 + lane] = sel;
}

// ---------------------------------------------------------------- K1: QKV + phi (1 row/block)
// Layouts: Qs[N][D] pre-scaled by SCL; Kq[D/4][N]{f4}; Vg[N][D];
//          phiQ[N][R]; phiKq[R/4][N]{f4}
__global__ __launch_bounds__(128) void qkv_phi_kernel(
    const float* __restrict__ Z,
    const float* __restrict__ Wq, const float* __restrict__ bq,
    const float* __restrict__ Wk, const float* __restrict__ bk,
    const float* __restrict__ Wv, const float* __restrict__ bv,
    const float* __restrict__ omega,
    float* __restrict__ Qs, float* __restrict__ Kq, float* __restrict__ Vg,
    float* __restrict__ phiQ, float* __restrict__ phiKq)
{
    __shared__ float Qn[D], Kn[D];
    const int i = blockIdx.x;
    const int t = threadIdx.x;

    if (t < 96) {
        const int which = t >> 5;
        const int c = t & 31;
        const float* W = (which == 0) ? Wq : (which == 1) ? Wk : Wv;
        const float* b = (which == 0) ? bq : (which == 1) ? bk : bv;
        float acc = b[c];
        #pragma unroll
        for (int k = 0; k < D; ++k) acc += Z[i * D + k] * W[k * D + c];
        if (which == 0) {
            Qs[i * D + c] = acc * SCL;
            float ss = acc * acc;
            #pragma unroll
            for (int m = 1; m <= 16; m <<= 1) ss += __shfl_xor(ss, m);
            Qn[c] = acc / fmaxf(sqrtf(ss), 1e-6f);
        } else if (which == 1) {
            Kq[(c >> 2) * (4 * N) + i * 4 + (c & 3)] = acc;   // f4-transposed
            float ss = acc * acc;
            #pragma unroll
            for (int m = 1; m <= 16; m <<= 1) ss += __shfl_xor(ss, m);
            Kn[c] = acc / fmaxf(sqrtf(ss), 1e-6f);
        } else {
            Vg[i * D + c] = acc;
        }
    }
    __syncthreads();
    {
        const int r = t & 63;
        const float* src = (t < 64) ? Qn : Kn;
        float dot = 0.f;
        #pragma unroll
        for (int k = 0; k < D; ++k) dot += src[k] * omega[k * R + r];
        const float ph = fexp2(dot * LOG2E) * 0.125f;
        if (t < 64) phiQ[i * R + r] = ph;
        else        phiKq[(r >> 2) * (4 * N) + i * 4 + (r & 3)] = ph;  // f4-transposed
    }
}

// ---------------------------------------------------------------- K2: scores + S@V partials
// S[i][j] = attendable ? esum : pdot   (low-rank folded in)
// Named-register bursts of 8 f4 columns (rule #20 safe), ES block then PD
// blocks (R13 ordering — interleave measured neutral).

#define ES_STEP(kk, u)                                                     \
    {                                                                      \
        _Pragma("unroll")                                                  \
        for (int i = 0; i < TI; ++i) {                                     \
            const f4 q4 = *(const f4*)(&Qls[i][4 * (u)]);                  \
            const f4 pr = (kk) * q4;                                       \
            es[i] += (f2){fexp2(pr.x) + fexp2(pr.z),                       \
                          fexp2(pr.y) + fexp2(pr.w)};                      \
        }                                                                  \
    }

#define PD_STEP(pk, v)                                                     \
    {                                                                      \
        _Pragma("unroll")                                                  \
        for (int i = 0; i < TI; ++i) {                                     \
            const f4 p4 = *(const f4*)(&Pls[i][4 * (v)]);                  \
            pd[i] += (f2){(pk).x, (pk).y} * (f2){p4.x, p4.y};              \
            pd[i] += (f2){(pk).z, (pk).w} * (f2){p4.z, p4.w};              \
        }                                                                  \
    }

__global__ __launch_bounds__(256, 2) void attn_kernel(
    const float* __restrict__ Qs, const float* __restrict__ Kq,
    const float* __restrict__ Vg, const float* __restrict__ phiQ,
    const float* __restrict__ phiKq,
    const unsigned long long* __restrict__ mb,
    float* __restrict__ part)        // [JS][N][D]
{
    __shared__ float S[TI][JT + 4];  // stride 260: rows land in distinct banks
    __shared__ f4 red[4][128];       // 8 KB
    __shared__ float Qls[TI][D];     // 2 KB broadcast Q rows (pre-scaled)
    __shared__ float Pls[TI][R];     // 4 KB broadcast phiQ rows
    const int t    = threadIdx.x;
    const int rg   = blockIdx.x / JS;
    const int js   = blockIdx.x % JS;
    const int row0 = rg * TI;
    const int j    = js * JT + t;
    const int lane = t & 63;
    const int wv   = t >> 6;

    // stage broadcast operands into LDS (contiguous global -> coalesced f2)
    ((f2*)Qls)[t]       = ((const f2*)(Qs + (size_t)row0 * D))[t];        // 512 floats
    ((f2*)Pls)[t]       = ((const f2*)(phiQ + (size_t)row0 * R))[t];      // 1024 floats
    ((f2*)Pls)[t + 256] = ((const f2*)(phiQ + (size_t)row0 * R))[t + 256];

    // wave-uniform packed-mask words
    unsigned long long wbits[TI];
    #pragma unroll
    for (int i = 0; i < TI; ++i)
        wbits[i] = mb[(size_t)(row0 + i) * NW + js * 4 + wv];

    const f4* K4 = (const f4*)Kq;     // [8][N]
    const f4* P4 = (const f4*)phiKq;  // [16][N]

    // burst-load all 8 K columns (named -> registers, one drain)
    const f4 ka = K4[(size_t)0 * N + j];
    const f4 kb = K4[(size_t)1 * N + j];
    const f4 kc = K4[(size_t)2 * N + j];
    const f4 kd = K4[(size_t)3 * N + j];
    const f4 ke = K4[(size_t)4 * N + j];
    const f4 kf = K4[(size_t)5 * N + j];
    const f4 kg = K4[(size_t)6 * N + j];
    const f4 kh = K4[(size_t)7 * N + j];

    __syncthreads();

    f2 es[TI], pd[TI];
    #pragma unroll
    for (int i = 0; i < TI; ++i) { es[i] = (f2){0.f, 0.f}; pd[i] = (f2){0.f, 0.f}; }

    ES_STEP(ka, 0) ES_STEP(kb, 1) ES_STEP(kc, 2) ES_STEP(kd, 3)
    ES_STEP(ke, 4) ES_STEP(kf, 5) ES_STEP(kg, 6) ES_STEP(kh, 7)

    {   // pd first half: burst 8 named phiK columns
        const f4 pa = P4[(size_t)0 * N + j];
        const f4 pb = P4[(size_t)1 * N + j];
        const f4 pc = P4[(size_t)2 * N + j];
        const f4 pdc = P4[(size_t)3 * N + j];
        const f4 pe = P4[(size_t)4 * N + j];
        const f4 pf = P4[(size_t)5 * N + j];
        const f4 pg = P4[(size_t)6 * N + j];
        const f4 ph = P4[(size_t)7 * N + j];
        PD_STEP(pa, 0) PD_STEP(pb, 1) PD_STEP(pc, 2) PD_STEP(pdc, 3)
        PD_STEP(pe, 4) PD_STEP(pf, 5) PD_STEP(pg, 6) PD_STEP(ph, 7)
    }
    {   // pd second half
        const f4 qa = P4[(size_t)8 * N + j];
        const f4 qb = P4[(size_t)9 * N + j];
        const f4 qc = P4[(size_t)10 * N + j];
        const f4 qd = P4[(size_t)11 * N + j];
        const f4 qe = P4[(size_t)12 * N + j];
        const f4 qf = P4[(size_t)13 * N + j];
        const f4 qg = P4[(size_t)14 * N + j];
        const f4 qh = P4[(size_t)15 * N + j];
        PD_STEP(qa, 8)  PD_STEP(qb, 9)  PD_STEP(qc, 10) PD_STEP(qd, 11)
        PD_STEP(qe, 12) PD_STEP(qf, 13) PD_STEP(qg, 14) PD_STEP(qh, 15)
    }

    #pragma unroll
    for (int i = 0; i < TI; ++i) {
        const float se = es[i].x + es[i].y;
        const float sp = pd[i].x + pd[i].y;
        const bool att = (wbits[i] >> lane) & 1ULL;
        S[i][t] = att ? se : sp;
    }
    __syncthreads();

    // phase 2: thread = (jg, i2, c4); handles rows i2 and i2+8
    const int jg = t >> 6;           // 0..3
    const int i2 = (t >> 3) & 7;     // 0..7
    const int c4 = t & 7;
    f4 acc0 = {0.f, 0.f, 0.f, 0.f};  // row i2
    f4 acc1 = {0.f, 0.f, 0.f, 0.f};  // row i2+8
    const f4* V4 = (const f4*)(Vg + (size_t)js * JT * D);
    #pragma unroll 8
    for (int n = 0; n < 64; ++n) {
        const int jj = jg * 64 + n;
        const f4 v = V4[jj * 8 + c4];
        acc0 += S[i2][jj]     * v;
        acc1 += S[i2 + 8][jj] * v;
    }
    red[jg][(i2 << 3) | c4]        = acc0;
    red[jg][64 | (i2 << 3) | c4]   = acc1;
    __syncthreads();
    if (t < 128) {
        const int idx = t;           // h*64 + (row_lo*8 + c4)
        const f4 rsum = (red[0][idx] + red[1][idx]) + (red[2][idx] + red[3][idx]);
        const int h   = idx >> 6;
        const int row = h * 8 + ((idx >> 3) & 7);
        const int cc  = idx & 7;
        *(f4*)(part + ((size_t)js * N + row0 + row) * D + cc * 4) = rsum;
    }
}

// ---------------------------------------------------------------- K3: epilogue (reduce + denom + Wo + LN + FFN + LN)
__global__ __launch_bounds__(256) void epilogue_kernel(
    const float* __restrict__ part, const float* __restrict__ Z,
    const float* __restrict__ Wo, const float* __restrict__ bo,
    const float* __restrict__ W1, const float* __restrict__ b1,
    const float* __restrict__ W2, const float* __restrict__ b2,
    const float* __restrict__ g1, const float* __restrict__ beta1,
    const float* __restrict__ g2, const float* __restrict__ beta2,
    float* __restrict__ out)
{
    const int i    = blockIdx.x * 4 + (threadIdx.x >> 6);
    const int lane = threadIdx.x & 63;
    const int c    = lane & 31;

    float a = 0.f;
    #pragma unroll
    for (int s = 0; s < JS; ++s) a += part[((size_t)s * N + i) * D + c];

    float s = a;
    #pragma unroll
    for (int m = 1; m <= 16; m <<= 1) s += __shfl_xor(s, m);
    const float an = a / fmaxf(s, 1e-6f);

    float o = bo[c];
    #pragma unroll
    for (int k = 0; k < D; ++k) o += __shfl(an, k) * Wo[k * D + c];

    float x = Z[i * D + c] + o;
    float mu = x;
    #pragma unroll
    for (int m = 1; m <= 16; m <<= 1) mu += __shfl_xor(mu, m);
    mu *= (1.0f / D);
    const float diff = x - mu;
    float var = diff * diff;
    #pragma unroll
    for (int m = 1; m <= 16; m <<= 1) var += __shfl_xor(var, m);
    var *= (1.0f / D);
    const float z1 = diff * rsqrtf(var + 1e-5f) * g1[c] + beta1[c];

    const int j0 = lane, j1 = lane + 64;
    float h0 = b1[j0], h1 = b1[j1];
    #pragma unroll
    for (int k = 0; k < D; ++k) {
        const float zk = __shfl(z1, k);
        h0 += zk * W1[k * 128 + j0];
        h1 += zk * W1[k * 128 + j1];
    }
    h0 = fmaxf(h0, 0.f); h1 = fmaxf(h1, 0.f);

    float y = b2[c];
    #pragma unroll
    for (int jj = 0; jj < 64; ++jj) {
        y += __shfl(h0, jj) * W2[jj * D + c];
        y += __shfl(h1, jj) * W2[(jj + 64) * D + c];
    }

    const float x2 = z1 + y;
    float mu2 = x2;
    #pragma unroll
    for (int m = 1; m <= 16; m <<= 1) mu2 += __shfl_xor(mu2, m);
    mu2 *= (1.0f / D);
    const float d2 = x2 - mu2;
    float v2 = d2 * d2;
    #pragma unroll
    for (int m = 1; m <= 16; m <<= 1) v2 += __shfl_xor(v2, m);
    v2 *= (1.0f / D);
    const float res = d2 * rsqrtf(v2 + 1e-5f) * g2[c] + beta2[c];

    if (lane < 32) out[i * D + c] = res;
}

// ----------------------------------------------------------------
extern "C" void kernel_launch(void* const* d_in, const int* in_sizes, int n_in,
                              void* d_out, int out_size, void* d_ws, size_t ws_size,
                              hipStream_t stream) {
    const float* Z     = (const float*)d_in[0];
    const int*   mask  = (const int*)d_in[1];
    const float* Wq    = (const float*)d_in[2];
    const float* bq    = (const float*)d_in[3];
    const float* Wk    = (const float*)d_in[4];
    const float* bk    = (const float*)d_in[5];
    const float* Wv    = (const float*)d_in[6];
    const float* bv    = (const float*)d_in[7];
    const float* Wo    = (const float*)d_in[8];
    const float* bo    = (const float*)d_in[9];
    const float* W1    = (const float*)d_in[10];
    const float* b1    = (const float*)d_in[11];
    const float* W2    = (const float*)d_in[12];
    const float* b2    = (const float*)d_in[13];
    const float* g1    = (const float*)d_in[14];
    const float* be1   = (const float*)d_in[15];
    const float* g2    = (const float*)d_in[16];
    const float* be2   = (const float*)d_in[17];
    const float* omega = (const float*)d_in[18];
    float* out = (float*)d_out;

    unsigned long long* mbw = (unsigned long long*)d_ws;   // N*NW u64 (512 KB)
    float* Qsw   = (float*)(mbw + (size_t)N * NW);         // N*D
    float* Kqw   = Qsw + N * D;                            // N*D
    float* Vw    = Kqw + N * D;                            // N*D
    float* pQ    = Vw + N * D;                             // N*R
    float* pKq   = pQ + N * R;                             // N*R
    float* partw = pKq + N * R;                            // JS*N*D

    mask_pack_kernel<<<(N * N) / 1024, 256, 0, stream>>>(mask, mbw);
    qkv_phi_kernel<<<N, 128, 0, stream>>>(Z, Wq, bq, Wk, bk, Wv, bv, omega,
                                          Qsw, Kqw, Vw, pQ, pKq);
    attn_kernel<<<(N / TI) * JS, 256, 0, stream>>>(Qsw, Kqw, Vw, pQ, pKq, mbw, partw);
    epilogue_kernel<<<N / 4, 256, 0, stream>>>(partw, Z, Wo, bo,
                                               W1, b1, W2, b2, g1, be1, g2, be2, out);
}

// Round 17
// 143.482 us; speedup vs baseline: 1.0976x; 1.0976x over previous
//
#include <hip/hip_runtime.h>
#include <math.h>

#define N 2048
#define D 32
#define R 64
#define TI 8            // rows per attn block
#define JS 8            // j-splits
#define JT (N / JS)     // 256 j's per block
#define NW (N / 64)     // 32 u64 mask words per row

// (1/sqrt(d)) * log2(e), folded into stored Q
#define SCL (0.17677669529663687f * 1.4426950408889634f)
#define LOG2E 1.4426950408889634f

typedef float f2 __attribute__((ext_vector_type(2)));
typedef float f4 __attribute__((ext_vector_type(4)));

static __device__ __forceinline__ float fexp2(float x) {
    return __builtin_amdgcn_exp2f(x);
}

// ---------------------------------------------------------------- K0: pack attendable(mask==0) into bits
__global__ __launch_bounds__(256) void mask_pack_kernel(
    const int* __restrict__ mask, unsigned long long* __restrict__ mb)
{
    const size_t w   = ((size_t)blockIdx.x * 256 + threadIdx.x) >> 6; // global wave id
    const int   lane = threadIdx.x & 63;
    const size_t base = w * 256;
    const unsigned long long w0 = __ballot(mask[base +   0 + lane] == 0);
    const unsigned long long w1 = __ballot(mask[base +  64 + lane] == 0);
    const unsigned long long w2 = __ballot(mask[base + 128 + lane] == 0);
    const unsigned long long w3 = __ballot(mask[base + 192 + lane] == 0);
    const unsigned long long sel = (lane == 0) ? w0 : (lane == 1) ? w1
                                 : (lane == 2) ? w2 : w3;
    if (lane < 4) mb[w * 4 + lane] = sel;
}

// ---------------------------------------------------------------- K1: QKV + phi (1 row/block)
// Layouts: Qs[N][D] pre-scaled by SCL; Kq[D/4][N]{f4}; Vg[N][D];
//          phiQ[N][R]; phiKq[R/4][N]{f4}
__global__ __launch_bounds__(128) void qkv_phi_kernel(
    const float* __restrict__ Z,
    const float* __restrict__ Wq, const float* __restrict__ bq,
    const float* __restrict__ Wk, const float* __restrict__ bk,
    const float* __restrict__ Wv, const float* __restrict__ bv,
    const float* __restrict__ omega,
    float* __restrict__ Qs, float* __restrict__ Kq, float* __restrict__ Vg,
    float* __restrict__ phiQ, float* __restrict__ phiKq)
{
    __shared__ float Qn[D], Kn[D];
    const int i = blockIdx.x;
    const int t = threadIdx.x;

    if (t < 96) {
        const int which = t >> 5;
        const int c = t & 31;
        const float* W = (which == 0) ? Wq : (which == 1) ? Wk : Wv;
        const float* b = (which == 0) ? bq : (which == 1) ? bk : bv;
        float acc = b[c];
        #pragma unroll
        for (int k = 0; k < D; ++k) acc += Z[i * D + k] * W[k * D + c];
        if (which == 0) {
            Qs[i * D + c] = acc * SCL;
            float ss = acc * acc;
            #pragma unroll
            for (int m = 1; m <= 16; m <<= 1) ss += __shfl_xor(ss, m);
            Qn[c] = acc / fmaxf(sqrtf(ss), 1e-6f);
        } else if (which == 1) {
            Kq[(c >> 2) * (4 * N) + i * 4 + (c & 3)] = acc;   // f4-transposed
            float ss = acc * acc;
            #pragma unroll
            for (int m = 1; m <= 16; m <<= 1) ss += __shfl_xor(ss, m);
            Kn[c] = acc / fmaxf(sqrtf(ss), 1e-6f);
        } else {
            Vg[i * D + c] = acc;
        }
    }
    __syncthreads();
    {
        const int r = t & 63;
        const float* src = (t < 64) ? Qn : Kn;
        float dot = 0.f;
        #pragma unroll
        for (int k = 0; k < D; ++k) dot += src[k] * omega[k * R + r];
        const float ph = fexp2(dot * LOG2E) * 0.125f;
        if (t < 64) phiQ[i * R + r] = ph;
        else        phiKq[(r >> 2) * (4 * N) + i * 4 + (r & 3)] = ph;  // f4-transposed
    }
}

// ---------------------------------------------------------------- K2: scores + S@V partials
// S[i][j] = attendable ? esum : pdot   (low-rank folded in)
// Named-register bursts of 8 f4 columns (rule #20 safe).

#define ES_STEP(kk, u)                                                     \
    {                                                                      \
        _Pragma("unroll")                                                  \
        for (int i = 0; i < TI; ++i) {                                     \
            const f4 q4 = *(const f4*)(&Qls[i][4 * (u)]);                  \
            const f4 pr = (kk) * q4;                                       \
            es[i] += (f2){fexp2(pr.x) + fexp2(pr.z),                       \
                          fexp2(pr.y) + fexp2(pr.w)};                      \
        }                                                                  \
    }

#define PD_STEP(pk, v)                                                     \
    {                                                                      \
        _Pragma("unroll")                                                  \
        for (int i = 0; i < TI; ++i) {                                     \
            const f4 p4 = *(const f4*)(&Pls[i][4 * (v)]);                  \
            pd[i] += (f2){(pk).x, (pk).y} * (f2){p4.x, p4.y};              \
            pd[i] += (f2){(pk).z, (pk).w} * (f2){p4.z, p4.w};              \
        }                                                                  \
    }

__global__ __launch_bounds__(256, 2) void attn_kernel(
    const float* __restrict__ Qs, const float* __restrict__ Kq,
    const float* __restrict__ Vg, const float* __restrict__ phiQ,
    const float* __restrict__ phiKq,
    const unsigned long long* __restrict__ mb,
    float* __restrict__ part)        // [JS][N][D]
{
    __shared__ float S[TI][JT + 4];  // +4 pad: 8 ii-rows land in 8 distinct banks
    __shared__ f4 red[4][64];
    __shared__ float Qls[TI][D];     // 1 KB broadcast Q rows (pre-scaled)
    __shared__ float Pls[TI][R];     // 2 KB broadcast phiQ rows
    const int t    = threadIdx.x;
    const int rg   = blockIdx.x / JS;
    const int js   = blockIdx.x % JS;
    const int row0 = rg * TI;
    const int j    = js * JT + t;
    const int lane = t & 63;
    const int wv   = t >> 6;

    // stage broadcast operands into LDS (contiguous global -> coalesced)
    ((float*)Qls)[t] = Qs[(size_t)row0 * D + t];
    ((float*)Pls)[t]       = phiQ[(size_t)row0 * R + t];
    ((float*)Pls)[t + 256] = phiQ[(size_t)row0 * R + t + 256];

    // wave-uniform packed-mask words -> s_load into SGPRs
    unsigned long long wbits[TI];
    #pragma unroll
    for (int i = 0; i < TI; ++i)
        wbits[i] = mb[(size_t)(row0 + i) * NW + js * 4 + wv];

    const f4* K4 = (const f4*)Kq;     // [8][N]
    const f4* P4 = (const f4*)phiKq;  // [16][N]

    // burst-load all 8 K columns (named -> registers, one drain)
    const f4 ka = K4[(size_t)0 * N + j];
    const f4 kb = K4[(size_t)1 * N + j];
    const f4 kc = K4[(size_t)2 * N + j];
    const f4 kd = K4[(size_t)3 * N + j];
    const f4 ke = K4[(size_t)4 * N + j];
    const f4 kf = K4[(size_t)5 * N + j];
    const f4 kg = K4[(size_t)6 * N + j];
    const f4 kh = K4[(size_t)7 * N + j];

    __syncthreads();

    f2 es[TI], pd[TI];
    #pragma unroll
    for (int i = 0; i < TI; ++i) { es[i] = (f2){0.f, 0.f}; pd[i] = (f2){0.f, 0.f}; }

    ES_STEP(ka, 0) ES_STEP(kb, 1) ES_STEP(kc, 2) ES_STEP(kd, 3)
    ES_STEP(ke, 4) ES_STEP(kf, 5) ES_STEP(kg, 6) ES_STEP(kh, 7)

    {   // pd first half: burst 8 named phiK columns
        const f4 pa = P4[(size_t)0 * N + j];
        const f4 pb = P4[(size_t)1 * N + j];
        const f4 pc = P4[(size_t)2 * N + j];
        const f4 pdc = P4[(size_t)3 * N + j];
        const f4 pe = P4[(size_t)4 * N + j];
        const f4 pf = P4[(size_t)5 * N + j];
        const f4 pg = P4[(size_t)6 * N + j];
        const f4 ph = P4[(size_t)7 * N + j];
        PD_STEP(pa, 0) PD_STEP(pb, 1) PD_STEP(pc, 2) PD_STEP(pdc, 3)
        PD_STEP(pe, 4) PD_STEP(pf, 5) PD_STEP(pg, 6) PD_STEP(ph, 7)
    }
    {   // pd second half
        const f4 pa = P4[(size_t)8 * N + j];
        const f4 pb = P4[(size_t)9 * N + j];
        const f4 pc = P4[(size_t)10 * N + j];
        const f4 pdc = P4[(size_t)11 * N + j];
        const f4 pe = P4[(size_t)12 * N + j];
        const f4 pf = P4[(size_t)13 * N + j];
        const f4 pg = P4[(size_t)14 * N + j];
        const f4 ph = P4[(size_t)15 * N + j];
        PD_STEP(pa, 8)  PD_STEP(pb, 9)  PD_STEP(pc, 10) PD_STEP(pdc, 11)
        PD_STEP(pe, 12) PD_STEP(pf, 13) PD_STEP(pg, 14) PD_STEP(ph, 15)
    }

    #pragma unroll
    for (int i = 0; i < TI; ++i) {
        const float se = es[i].x + es[i].y;
        const float sp = pd[i].x + pd[i].y;
        const bool att = (wbits[i] >> lane) & 1ULL;
        S[i][t] = att ? se : sp;
    }
    __syncthreads();

    // phase 2: thread = (jg, ii, c4); 2 accumulators break the FMA chain
    const int jg = t >> 6;
    const int ii = (t >> 3) & 7;
    const int c4 = t & 7;
    f4 acc0 = {0.f, 0.f, 0.f, 0.f};
    f4 acc1 = {0.f, 0.f, 0.f, 0.f};
    const f4* V4 = (const f4*)(Vg + (size_t)js * JT * D);
    #pragma unroll 8
    for (int n = 0; n < 64; n += 2) {
        const int jj = jg * 64 + n;
        acc0 += S[ii][jj]     * V4[jj * 8 + c4];
        acc1 += S[ii][jj + 1] * V4[(jj + 1) * 8 + c4];
    }
    red[jg][t & 63] = acc0 + acc1;
    __syncthreads();
    if (t < 64) {
        const f4 rsum = (red[0][t] + red[1][t]) + (red[2][t] + red[3][t]);
        *(f4*)(part + ((size_t)js * N + row0 + (t >> 3)) * D + (t & 7) * 4) = rsum;
    }
}

// ---------------------------------------------------------------- K3: epilogue (reduce + denom + Wo + LN + FFN + LN)
__global__ __launch_bounds__(256) void epilogue_kernel(
    const float* __restrict__ part, const float* __restrict__ Z,
    const float* __restrict__ Wo, const float* __restrict__ bo,
    const float* __restrict__ W1, const float* __restrict__ b1,
    const float* __restrict__ W2, const float* __restrict__ b2,
    const float* __restrict__ g1, const float* __restrict__ beta1,
    const float* __restrict__ g2, const float* __restrict__ beta2,
    float* __restrict__ out)
{
    const int i    = blockIdx.x * 4 + (threadIdx.x >> 6);
    const int lane = threadIdx.x & 63;
    const int c    = lane & 31;

    float a = 0.f;
    #pragma unroll
    for (int s = 0; s < JS; ++s) a += part[((size_t)s * N + i) * D + c];

    float s = a;
    #pragma unroll
    for (int m = 1; m <= 16; m <<= 1) s += __shfl_xor(s, m);
    const float an = a / fmaxf(s, 1e-6f);

    float o = bo[c];
    #pragma unroll
    for (int k = 0; k < D; ++k) o += __shfl(an, k) * Wo[k * D + c];

    float x = Z[i * D + c] + o;
    float mu = x;
    #pragma unroll
    for (int m = 1; m <= 16; m <<= 1) mu += __shfl_xor(mu, m);
    mu *= (1.0f / D);
    const float diff = x - mu;
    float var = diff * diff;
    #pragma unroll
    for (int m = 1; m <= 16; m <<= 1) var += __shfl_xor(var, m);
    var *= (1.0f / D);
    const float z1 = diff * rsqrtf(var + 1e-5f) * g1[c] + beta1[c];

    const int j0 = lane, j1 = lane + 64;
    float h0 = b1[j0], h1 = b1[j1];
    #pragma unroll
    for (int k = 0; k < D; ++k) {
        const float zk = __shfl(z1, k);
        h0 += zk * W1[k * 128 + j0];
        h1 += zk * W1[k * 128 + j1];
    }
    h0 = fmaxf(h0, 0.f); h1 = fmaxf(h1, 0.f);

    float y = b2[c];
    #pragma unroll
    for (int jj = 0; jj < 64; ++jj) {
        y += __shfl(h0, jj) * W2[jj * D + c];
        y += __shfl(h1, jj) * W2[(jj + 64) * D + c];
    }

    const float x2 = z1 + y;
    float mu2 = x2;
    #pragma unroll
    for (int m = 1; m <= 16; m <<= 1) mu2 += __shfl_xor(mu2, m);
    mu2 *= (1.0f / D);
    const float d2 = x2 - mu2;
    float v2 = d2 * d2;
    #pragma unroll
    for (int m = 1; m <= 16; m <<= 1) v2 += __shfl_xor(v2, m);
    v2 *= (1.0f / D);
    const float res = d2 * rsqrtf(v2 + 1e-5f) * g2[c] + beta2[c];

    if (lane < 32) out[i * D + c] = res;
}

// ----------------------------------------------------------------
extern "C" void kernel_launch(void* const* d_in, const int* in_sizes, int n_in,
                              void* d_out, int out_size, void* d_ws, size_t ws_size,
                              hipStream_t stream) {
    const float* Z     = (const float*)d_in[0];
    const int*   mask  = (const int*)d_in[1];
    const float* Wq    = (const float*)d_in[2];
    const float* bq    = (const float*)d_in[3];
    const float* Wk    = (const float*)d_in[4];
    const float* bk    = (const float*)d_in[5];
    const float* Wv    = (const float*)d_in[6];
    const float* bv    = (const float*)d_in[7];
    const float* Wo    = (const float*)d_in[8];
    const float* bo    = (const float*)d_in[9];
    const float* W1    = (const float*)d_in[10];
    const float* b1    = (const float*)d_in[11];
    const float* W2    = (const float*)d_in[12];
    const float* b2    = (const float*)d_in[13];
    const float* g1    = (const float*)d_in[14];
    const float* be1   = (const float*)d_in[15];
    const float* g2    = (const float*)d_in[16];
    const float* be2   = (const float*)d_in[17];
    const float* omega = (const float*)d_in[18];
    float* out = (float*)d_out;

    unsigned long long* mbw = (unsigned long long*)d_ws;   // N*NW u64 (512 KB)
    float* Qsw   = (float*)(mbw + (size_t)N * NW);         // N*D
    float* Kqw   = Qsw + N * D;                            // N*D
    float* Vw    = Kqw + N * D;                            // N*D
    float* pQ    = Vw + N * D;                             // N*R
    float* pKq   = pQ + N * R;                             // N*R
    float* partw = pKq + N * R;                            // JS*N*D

    mask_pack_kernel<<<(N * N) / 1024, 256, 0, stream>>>(mask, mbw);
    qkv_phi_kernel<<<N, 128, 0, stream>>>(Z, Wq, bq, Wk, bk, Wv, bv, omega,
                                          Qsw, Kqw, Vw, pQ, pKq);
    attn_kernel<<<(N / TI) * JS, 256, 0, stream>>>(Qsw, Kqw, Vw, pQ, pKq, mbw, partw);
    epilogue_kernel<<<N / 4, 256, 0, stream>>>(partw, Z, Wo, bo,
                                               W1, b1, W2, b2, g1, be1, g2, be2, out);
}